// Round 10
// baseline (84.291 us; speedup 1.0000x reference)
//
#include <hip/hip_runtime.h>

#define SEQ 128
#define DM 32

// log2(e) * 2^23 : natural-exponent slope -> float-exponent-bit units
#define K_LOG2E_2P23 12102203.161561485f
// Schraudolph bias: (127 - 0.04384) * 2^23, minimax-balanced rel error (+/- ~3%)
#define SCHRAUDOLPH_C 1064985472.0f
#define INV_SQRT_D 0.17677669529663687f  // 1/sqrt(32)

// ---------------------------------------------------------------------------
// DPP wave reductions (VALU pipe; keeps the LDS unit free).
// Classic gfx9 chain: row_shr 1/2/4/8 then row_bcast15/31; lane 63 holds the
// full 64-lane result.
// ---------------------------------------------------------------------------
template <int ctrl, bool zero>
__device__ __forceinline__ float dppf(float v) {
    return __int_as_float(__builtin_amdgcn_update_dpp(
        zero ? 0 : __float_as_int(v), __float_as_int(v), ctrl, 0xf, 0xf, zero));
}

__device__ __forceinline__ float wred_max(float v) {
    v = fmaxf(v, dppf<0x111, false>(v));
    v = fmaxf(v, dppf<0x112, false>(v));
    v = fmaxf(v, dppf<0x114, false>(v));
    v = fmaxf(v, dppf<0x118, false>(v));
    v = fmaxf(v, dppf<0x142, false>(v));
    v = fmaxf(v, dppf<0x143, false>(v));
    return __int_as_float(__builtin_amdgcn_readlane(__float_as_int(v), 63));
}

__device__ __forceinline__ float wred_min(float v) {
    v = fminf(v, dppf<0x111, false>(v));
    v = fminf(v, dppf<0x112, false>(v));
    v = fminf(v, dppf<0x114, false>(v));
    v = fminf(v, dppf<0x118, false>(v));
    v = fminf(v, dppf<0x142, false>(v));
    v = fminf(v, dppf<0x143, false>(v));
    return __int_as_float(__builtin_amdgcn_readlane(__float_as_int(v), 63));
}

// inclusive chain; lane 63 ends with the full 64-lane sum
__device__ __forceinline__ float wred_sum_lane63(float v) {
    v += dppf<0x111, true>(v);
    v += dppf<0x112, true>(v);
    v += dppf<0x114, true>(v);
    v += dppf<0x118, true>(v);
    v += dppf<0x142, true>(v);
    v += dppf<0x143, true>(v);
    return v;
}

// ---------------------------------------------------------------------------
// Table-point partial series over a QUARTER of the row (32 k's): S = sum e_k,
// U = sum e_k x_k at this lane's t-point. Lane quads share a t-point and
// split the k-range; reads rotated by 2*(lane&3) so the quad's 4 distinct
// float4 addresses are bank-disjoint (conflict-free; m136).
// Schraudolph fast-exp: e = bitcast(int(Tp*x + Mp)); CLAMP guards
// int-underflow for rare high-dynamic-range rows (wave-uniform branch).
// ---------------------------------------------------------------------------
template <bool CLAMP>
__device__ __forceinline__ void table_loop_quarter(const float4* __restrict__ base,
                                                   int rot, float Tp, float Mp,
                                                   float& S, float& U) {
#pragma unroll
    for (int i = 0; i < 8; ++i) {
        const float4 xv = base[(rot + i) & 7];  // ds_read_b128, skewed
#pragma unroll
        for (int j = 0; j < 4; ++j) {
            const float xk = (j == 0) ? xv.x : (j == 1) ? xv.y : (j == 2) ? xv.z : xv.w;
            float v = fmaf(Tp, xk, Mp);
            if (CLAMP) v = fmaxf(v, 0.0f);
            const float e = __int_as_float((int)v);
            S += e;
            U = fmaf(e, xk, U);
        }
    }
}

// ---------------------------------------------------------------------------
// Single fused kernel. Algebra (R0): tokens are affine in the scalar x[b,s],
// so the attention collapses to out[b] = alpha * mean_q m(t_q) + beta with
// m(t) = sum_k x_k e^{t x_k} / sum_k e^{t x_k}, t_q = a*x_q + c; 4 scalars
// folded from the weights (K-bias cancels in softmax).
//
// Fold placement (R3/R5/R9 post-mortems): per-wave fold kills TLP; a
// separate 1-block kernel costs a dispatch + graph-node gap. Here wave 0
// folds per block -- its ~80 weight loads (L1/L2-hot after gen 1) complete
// inside the ~900-cyc HBM latency of the x-row loads that ALL waves must
// absorb anyway, so the __syncthreads costs ~nothing.
//
// m(t) evaluated via 16-point table (lane quad -> point, ghosts at 0/15,
// 13 interior cells) + Catmull-Rom cubic from LDS. Error anchor: exact, 61-,
// 29- and 13-cell all gave bit-identical absmax (interp error invisible
// under the 3% Schraudolph floor, which itself largely cancels in the
// softmax ratio).
// ---------------------------------------------------------------------------
#define WAVES_PER_BLOCK 4
#define NPTS 16

__global__ __launch_bounds__(256) void attn_fused_kernel(
        const float* __restrict__ x,
        const float* __restrict__ Wt, const float* __restrict__ bt,
        const float* __restrict__ Wq, const float* __restrict__ bq,
        const float* __restrict__ Wk,
        const float* __restrict__ Wv, const float* __restrict__ bv,
        const float* __restrict__ Wo, const float* __restrict__ bo,
        float* __restrict__ out, int B) {
    __shared__ float sx[WAVES_PER_BLOCK][SEQ];
    __shared__ float tab[WAVES_PER_BLOCK][NPTS];
    __shared__ float sconsts[4];

    const int wave = threadIdx.x >> 6;
    const int lane = threadIdx.x & 63;
    int b = blockIdx.x * WAVES_PER_BLOCK + wave;
    if (b >= B) b = B - 1;  // tail dup; idempotent writes

    // ---- every wave: stage its row (the ~900-cyc HBM wait all waves pay) ----
    const float* xr = x + (size_t)b * SEQ;
    const float x0 = xr[lane];
    const float x1 = xr[lane + 64];
    sx[wave][lane]      = x0;
    sx[wave][lane + 64] = x1;

    // row max/min via DPP chains (VALU pipe)
    const float mx = wred_max(fmaxf(x0, x1));
    const float mn = wred_min(fminf(x0, x1));

    // ---- wave 0: fold weights to 4 scalars (hides under x-load latency) ----
    if (wave == 0) {
        const int e  = lane & 31;
        const int dh = lane >> 5;  // 0 or 1
        float qw = 0.f, qb = 0.f, kw = 0.f, vw = 0.f, vb = 0.f;
#pragma unroll
        for (int i = 0; i < 16; ++i) {
            const int d = dh * 16 + i;
            const float wt  = Wt[d];
            const float bb  = bt[d];
            const float wqe = Wq[d * DM + e];
            const float wke = Wk[d * DM + e];
            const float wve = Wv[d * DM + e];
            qw = fmaf(wt, wqe, qw); qb = fmaf(bb, wqe, qb);
            kw = fmaf(wt, wke, kw);
            vw = fmaf(wt, wve, vw); vb = fmaf(bb, wve, vb);
        }
        // combine the two d-halves (each e present in 2 lanes, identical after)
        qw += __shfl_xor(qw, 32); qb += __shfl_xor(qb, 32);
        kw += __shfl_xor(kw, 32);
        vw += __shfl_xor(vw, 32); vb += __shfl_xor(vb, 32);
        qb += bq[e];
        vb += bv[e];
        const float wo = Wo[e];
        float pa  = qw * kw;
        float pc  = qb * kw;
        float pal = vw * wo;
        float pbe = vb * wo;
#pragma unroll
        for (int off = 32; off > 0; off >>= 1) {
            pa  += __shfl_xor(pa,  off);
            pc  += __shfl_xor(pc,  off);
            pal += __shfl_xor(pal, off);
            pbe += __shfl_xor(pbe, off);
        }
        // 64-lane sum double-counts each e -> *0.5
        if (lane == 0) {
            sconsts[0] = pa * (0.5f * INV_SQRT_D * K_LOG2E_2P23);  // A
            sconsts[1] = pc * (0.5f * INV_SQRT_D * K_LOG2E_2P23);  // C
            sconsts[2] = pal * 0.5f;                               // alpha
            sconsts[3] = fmaf(pbe, 0.5f, bo[0]);                   // beta
        }
    }

    __syncthreads();

    const float A     = sconsts[0];
    const float C     = sconsts[1];
    const float alpha = sconsts[2];
    const float beta  = sconsts[3];

    // t-range over this row's q values (exp-bit units)
    const float Ta = fmaf(A, mn, C);
    const float Tb = fmaf(A, mx, C);
    const float Tlo = fminf(Ta, Tb);
    const float Thi = fmaxf(Ta, Tb);
    const float spanT = Thi - Tlo;
    const float h = spanT * (1.0f / 13.0f);
    const float invh = (spanT > 1e-6f) ? (13.0f / spanT) : 0.0f;

    // lane quad -> table point p: T_p = Tlo + (p-1)*h (p=0,15 = ghosts)
    const int p   = lane >> 2;
    const int c4  = lane & 3;   // which quarter of the row this lane sums
    const float Tp = fmaf((float)(p - 1), h, Tlo);
    const float Mp = SCHRAUDOLPH_C - fmaxf(Tp * mx, Tp * mn);

    float S = 0.f, U = 0.f;
    const float4* base = (const float4*)sx[wave] + (c4 << 3);
    const int rot = c4 << 1;

    // wave-uniform overflow-risk check over the extreme (ghost) table points
    const float maxTpt = fmaxf(fabsf(Tlo - h), fabsf(Thi + h));
    if (maxTpt * (mx - mn) < 1.0e9f) {
        table_loop_quarter<false>(base, rot, Tp, Mp, S, U);
    } else {
        table_loop_quarter<true>(base, rot, Tp, Mp, S, U);
    }

    // combine the four k-quarters within the lane quad (xor 1,2 -> DPP)
    S += __shfl_xor(S, 1);
    U += __shfl_xor(U, 1);
    S += __shfl_xor(S, 2);
    U += __shfl_xor(U, 2);

    // all 4 lanes of the quad write the same value to the same slot
    tab[wave][p] = U * __builtin_amdgcn_rcpf(S);

    // ---- Catmull-Rom interpolation for this lane's two q values ----
    const float t0 = fmaf(A, x0, C);
    const float t1 = fmaf(A, x1, C);
    float msum = 0.f;
#pragma unroll
    for (int r = 0; r < 2; ++r) {
        const float t = r ? t1 : t0;
        float u = (t - Tlo) * invh;           // in [0, 13] by construction
        u = fminf(fmaxf(u, 0.0f), 13.0f);     // safety clamp
        int c = (int)u;                        // cell index
        c = (c > 12) ? 12 : c;
        const float f = u - (float)c;          // in [0, 1]
        // CR nodes: tab[c..c+3] (cell spans points c+1 .. c+2)
        const float* tb = &tab[wave][c];
        const float p0 = tb[0], p1 = tb[1], p2 = tb[2], p3 = tb[3];
        const float d1 = p2 - p0;
        const float c2 = 2.0f * p0 - 5.0f * p1 + 4.0f * p2 - p3;
        const float c3 = 3.0f * (p1 - p2) + (p3 - p0);
        msum += fmaf(0.5f * f, fmaf(f, fmaf(f, c3, c2), d1), p1);
    }

    // mean over the row's 128 q via DPP sum; lane 63 holds the total
    msum = wred_sum_lane63(msum);
    if (lane == 63)
        out[b] = fmaf(alpha, msum * (1.0f / 128.0f), beta);
}

extern "C" void kernel_launch(void* const* d_in, const int* in_sizes, int n_in,
                              void* d_out, int out_size, void* d_ws, size_t ws_size,
                              hipStream_t stream) {
    const float* x  = (const float*)d_in[0];
    const float* Wt = (const float*)d_in[1];
    const float* bt = (const float*)d_in[2];
    const float* Wq = (const float*)d_in[3];
    const float* bq = (const float*)d_in[4];
    const float* Wk = (const float*)d_in[5];
    // bk (d_in[6]) provably cancels in softmax -> unused
    const float* Wv = (const float*)d_in[7];
    const float* bv = (const float*)d_in[8];
    const float* Wo = (const float*)d_in[9];
    const float* bo = (const float*)d_in[10];
    float* out = (float*)d_out;

    const int B = in_sizes[0] / SEQ;

    const int grid = (B + WAVES_PER_BLOCK - 1) / WAVES_PER_BLOCK;
    attn_fused_kernel<<<grid, 256, 0, stream>>>(x, Wt, bt, Wq, bq, Wk,
                                                Wv, bv, Wo, bo, out, B);
}